// Round 11
// baseline (103.404 us; speedup 1.0000x reference)
//
#include <hip/hip_runtime.h>
#include <math.h>

#define T_STEPS 22
#define F_IN    12
#define HID     32

typedef __attribute__((ext_vector_type(8))) short  bf16x8;
typedef __attribute__((ext_vector_type(4)))  float f32x4;
typedef __attribute__((ext_vector_type(2)))  float f32x2;

union FragU { unsigned int u[4]; bf16x8 v; };

#define LOG2E    1.442695041f
#define TWOLOG2E 2.885390082f

static __device__ __forceinline__ unsigned short f2bf(float x) {
    unsigned int u = __builtin_bit_cast(unsigned int, x);
    return (unsigned short)((u + 0x7fffu + ((u >> 16) & 1u)) >> 16);
}

static __device__ __forceinline__ unsigned cvt_pk_bf16(float lo, float hi) {
    unsigned r;
    asm("v_cvt_pk_bf16_f32 %0, %1, %2" : "=v"(r) : "v"(lo), "v"(hi));
    return r;
}

// 16x16x32 layout: A row = lane&15, k = 8*(lane>>4)+j. C col = lane&15,
// row = 4*(lane>>4)+reg. Gate tiles: i=0,1 | f=2,3 | g=4,5 | o=6,7.
// chat(k) column permutation (k=8s+j): j<4 -> 4s+j, j>=4 -> 16+4s+(j-4).
// Whh cols stored chat-permuted => lane's computed h rows {4s+q,16+4s+q}
// are exactly its next-step B-frag k-slots: ZERO-shuffle repack (verified r8).
//
// ws layout (floats):
//   [0,2048)    wx16: [8 tile][64 lane] x 8 bf16, rows prescaled; k=12 = fused bias
//   [2048,4096) wh16: [8 tile][64 lane] x 8 bf16, cols chat-permuted, prescaled
//   [4096,4128) whd:  [4 s][8 j] f32; j<4 -> Whead[4s+j], j>=4 -> Whead[16+4s+j-4]
__global__ void prep_kernel(const float* __restrict__ Wih, const float* __restrict__ Whh,
                            const float* __restrict__ bih, const float* __restrict__ bhh,
                            const float* __restrict__ Whead, float* __restrict__ ws) {
    const int tid = threadIdx.x;  // 256
    unsigned short* wx = (unsigned short*)ws;
    unsigned short* wh = (unsigned short*)(ws + 2048);
    float* whd = ws + 4096;

    for (int e = tid; e < 512; e += 256) {
        int tile = e >> 6, lane = e & 63;
        int row = lane & 15, s = lane >> 4;
        int g = 16 * tile + row;
        float scale = (tile == 4 || tile == 5) ? TWOLOG2E : -LOG2E;  // g-gate: +2log2e
        for (int j = 0; j < 8; ++j) {
            int k = 8 * s + j;
            float v = 0.0f;
            if (k < F_IN)       v = Wih[g * F_IN + k];
            else if (k == F_IN) v = bih[g] + bhh[g];
            wx[e * 8 + j] = f2bf(scale * v);
            int cc = (j < 4) ? (4 * s + j) : (16 + 4 * s + (j - 4));  // chat(k)
            wh[e * 8 + j] = f2bf(scale * Whh[g * HID + cc]);
        }
    }
    if (tid < 32) {
        int s = tid >> 3, j = tid & 7;
        int orig = (j < 4) ? (4 * s + j) : (16 + 4 * s + (j - 4));
        whd[tid] = Whead[orig];
    }
}

// 16 batch cols/wave, 8 gate tiles, 32 acc regs, weights in LDS (r8 structure,
// 57% occupancy proven) + fused-rcp packed cell (r9/r10, 7 trans/unit proven).
__global__ void __launch_bounds__(256, 2)
lstm_kernel(const float* __restrict__ x, const float* __restrict__ ws,
            const float* __restrict__ bheadp, float* __restrict__ out, int B) {
    const int tid  = threadIdx.x;
    const int lane = tid & 63;
    const int wave = tid >> 6;
    const int col  = lane & 15;
    const int s    = lane >> 4;
    int b = blockIdx.x * 64 + wave * 16 + col;
    const bool valid = (b < B);
    if (b >= B) b = B - 1;      // clamp; keep all threads in barriers

    __shared__ float wlds[4096];    // 16 KB: wx [0,2048), wh [2048,4096)
#pragma unroll
    for (int i = 0; i < 4; ++i)
        ((float4*)wlds)[tid + i * 256] = ((const float4*)ws)[tid + i * 256];
    __syncthreads();

    const bf16x8* wx_l = (const bf16x8*)wlds;           // [8][64]
    const bf16x8* wh_l = ((const bf16x8*)wlds) + 512;   // [8][64]

    // x B-frag k-slots: s=0 -> x[0..7]; s=1 -> x[8..11], k12=bias, rest 0;
    // s>=2 -> all zero (their weight cols are zero too).
    const float* xr  = x + (size_t)b * (T_STEPS * F_IN);
    const float* xa  = xr + ((s == 0) ? 0 : 8);
    const float* xbp = xr + ((s == 0) ? 4 : 8);

    f32x2 cc[4], hv[4];   // .x = units 4s+q (tiles even), .y = units 16+4s+q (odd)
#pragma unroll
    for (int q = 0; q < 4; ++q) { cc[q] = (f32x2){0.f, 0.f}; hv[q] = (f32x2){0.f, 0.f}; }
    bf16x8 hf;
#pragma unroll
    for (int j = 0; j < 8; ++j) hf[j] = 0;

    f32x4 zc;   // hoisted zero C-in
#pragma unroll
    for (int q = 0; q < 4; ++q) zc[q] = 0.0f;

#pragma unroll 1
    for (int t = 0; t < T_STEPS; ++t) {
        asm volatile("" ::: "memory");   // per-iteration LDS frag reads (no LICM blowup)

        float4 va = *(const float4*)(xa  + t * F_IN);
        float4 vb = *(const float4*)(xbp + t * F_IN);
        unsigned p0 = cvt_pk_bf16(va.x, va.y);
        unsigned p1 = cvt_pk_bf16(va.z, va.w);
        unsigned p2 = cvt_pk_bf16(vb.x, vb.y);
        unsigned p3 = cvt_pk_bf16(vb.z, vb.w);
        FragU xf;
        if (s == 0)      { xf.u[0] = p0; xf.u[1] = p1; xf.u[2] = p2;          xf.u[3] = p3; }
        else if (s == 1) { xf.u[0] = p0; xf.u[1] = p1; xf.u[2] = 0x00003f80u; xf.u[3] = 0;  }
        else             { xf.u[0] = 0;  xf.u[1] = 0;  xf.u[2] = 0;           xf.u[3] = 0;  }

        f32x4 a0, a1, a2, a3, a4, a5, a6, a7;
        a0 = __builtin_amdgcn_mfma_f32_16x16x32_bf16(wx_l[0 * 64 + lane], xf.v, zc, 0, 0, 0);
        a1 = __builtin_amdgcn_mfma_f32_16x16x32_bf16(wx_l[1 * 64 + lane], xf.v, zc, 0, 0, 0);
        a2 = __builtin_amdgcn_mfma_f32_16x16x32_bf16(wx_l[2 * 64 + lane], xf.v, zc, 0, 0, 0);
        a3 = __builtin_amdgcn_mfma_f32_16x16x32_bf16(wx_l[3 * 64 + lane], xf.v, zc, 0, 0, 0);
        a4 = __builtin_amdgcn_mfma_f32_16x16x32_bf16(wx_l[4 * 64 + lane], xf.v, zc, 0, 0, 0);
        a5 = __builtin_amdgcn_mfma_f32_16x16x32_bf16(wx_l[5 * 64 + lane], xf.v, zc, 0, 0, 0);
        a6 = __builtin_amdgcn_mfma_f32_16x16x32_bf16(wx_l[6 * 64 + lane], xf.v, zc, 0, 0, 0);
        a7 = __builtin_amdgcn_mfma_f32_16x16x32_bf16(wx_l[7 * 64 + lane], xf.v, zc, 0, 0, 0);
        a0 = __builtin_amdgcn_mfma_f32_16x16x32_bf16(wh_l[0 * 64 + lane], hf, a0, 0, 0, 0);
        a1 = __builtin_amdgcn_mfma_f32_16x16x32_bf16(wh_l[1 * 64 + lane], hf, a1, 0, 0, 0);
        a2 = __builtin_amdgcn_mfma_f32_16x16x32_bf16(wh_l[2 * 64 + lane], hf, a2, 0, 0, 0);
        a3 = __builtin_amdgcn_mfma_f32_16x16x32_bf16(wh_l[3 * 64 + lane], hf, a3, 0, 0, 0);
        a4 = __builtin_amdgcn_mfma_f32_16x16x32_bf16(wh_l[4 * 64 + lane], hf, a4, 0, 0, 0);
        a5 = __builtin_amdgcn_mfma_f32_16x16x32_bf16(wh_l[5 * 64 + lane], hf, a5, 0, 0, 0);
        a6 = __builtin_amdgcn_mfma_f32_16x16x32_bf16(wh_l[6 * 64 + lane], hf, a6, 0, 0, 0);
        a7 = __builtin_amdgcn_mfma_f32_16x16x32_bf16(wh_l[7 * 64 + lane], hf, a7, 0, 0, 0);
        // loose staging bound: {8 ds_read, 8 mfma} x 2 (window ~32 regs, no micro-pinning)
        __builtin_amdgcn_sched_group_barrier(0x100, 8, 0);
        __builtin_amdgcn_sched_group_barrier(0x008, 8, 0);
        __builtin_amdgcn_sched_group_barrier(0x100, 8, 0);
        __builtin_amdgcn_sched_group_barrier(0x008, 8, 0);

        // Fused-rcp cell (7 trans/unit), f32x2-packed across the two unit halves:
        //   A = (1+ei)(1+eg), F = (1+ef)
        //   c' = [2L*(eg-1)*F + c'*A] * rcp(F*A)
        //   h  = (ec-1) * rcp((1+eo)(1+ec)),  ec = exp2(c')
        const f32x2 one2 = {1.0f, 1.0f};
#pragma unroll
        for (int q = 0; q < 4; ++q) {
            f32x2 ei = {__builtin_amdgcn_exp2f(a0[q]), __builtin_amdgcn_exp2f(a1[q])};
            f32x2 ef = {__builtin_amdgcn_exp2f(a2[q]), __builtin_amdgcn_exp2f(a3[q])};
            f32x2 eg = {__builtin_amdgcn_exp2f(a4[q]), __builtin_amdgcn_exp2f(a5[q])};
            f32x2 eo = {__builtin_amdgcn_exp2f(a6[q]), __builtin_amdgcn_exp2f(a7[q])};
            f32x2 A  = (one2 + ei) * (one2 + eg);
            f32x2 F  = one2 + ef;
            f32x2 FA = F * A;
            f32x2 r1 = {__builtin_amdgcn_rcpf(FA.x), __builtin_amdgcn_rcpf(FA.y)};
            f32x2 t2 = eg * (f32x2){TWOLOG2E, TWOLOG2E} - (f32x2){TWOLOG2E, TWOLOG2E};
            f32x2 num = t2 * F + cc[q] * A;
            cc[q] = num * r1;
            f32x2 ec = {__builtin_amdgcn_exp2f(cc[q].x), __builtin_amdgcn_exp2f(cc[q].y)};
            f32x2 r2in = (one2 + eo) * (one2 + ec);
            f32x2 r2 = {__builtin_amdgcn_rcpf(r2in.x), __builtin_amdgcn_rcpf(r2in.y)};
            hv[q] = (ec - one2) * r2;
        }

        // zero-shuffle repack (chat-permutation): k-slots j<4 from .x, j>=4 from .y
        FragU hh;
        hh.u[0] = cvt_pk_bf16(hv[0].x, hv[1].x);
        hh.u[1] = cvt_pk_bf16(hv[2].x, hv[3].x);
        hh.u[2] = cvt_pk_bf16(hv[0].y, hv[1].y);
        hh.u[3] = cvt_pk_bf16(hv[2].y, hv[3].y);
        hf = hh.v;
    }

    // head: y = h . Whead + bhead ; softplus. Reduce over the 4 s-groups.
    const float* whd = ws + 4096 + s * 8;
    float y = 0.0f;
#pragma unroll
    for (int j = 0; j < 4; ++j) {
        y = fmaf(hv[j].x, whd[j],     y);
        y = fmaf(hv[j].y, whd[4 + j], y);
    }
    y += __shfl_xor(y, 16, 64);
    y += __shfl_xor(y, 32, 64);
    y += bheadp[0];
    float sp = fmaxf(y, 0.0f) + log1pf(expf(-fabsf(y)));
    if (valid && s == 0) out[b] = sp;
}

extern "C" void kernel_launch(void* const* d_in, const int* in_sizes, int n_in,
                              void* d_out, int out_size, void* d_ws, size_t ws_size,
                              hipStream_t stream) {
    const float* x     = (const float*)d_in[0];
    const float* Wih   = (const float*)d_in[1];
    const float* Whh   = (const float*)d_in[2];
    const float* bih   = (const float*)d_in[3];
    const float* bhh   = (const float*)d_in[4];
    const float* Whead = (const float*)d_in[5];
    const float* bhead = (const float*)d_in[6];
    float* out = (float*)d_out;
    float* ws  = (float*)d_ws;

    const int B = in_sizes[0] / (T_STEPS * F_IN);
    const int blocks = (B + 63) / 64;

    hipLaunchKernelGGL(prep_kernel, dim3(1), dim3(256), 0, stream,
                       Wih, Whh, bih, bhh, Whead, ws);
    hipLaunchKernelGGL(lstm_kernel, dim3(blocks), dim3(256), 0, stream,
                       x, ws, bhead, out, B);
}

// Round 12
// 85.537 us; speedup vs baseline: 1.2089x; 1.2089x over previous
//
#include <hip/hip_runtime.h>
#include <math.h>

#define T_STEPS 22
#define F_IN    12
#define HID     32

typedef __attribute__((ext_vector_type(8))) short  bf16x8;
typedef __attribute__((ext_vector_type(16))) float f32x16;
typedef __attribute__((ext_vector_type(2)))  float f32x2;

union FragU { unsigned int u[4]; bf16x8 v; };

#define LOG2E    1.442695041f
#define TWOLOG2E 2.885390082f

static __device__ __forceinline__ unsigned short f2bf(float x) {
    unsigned int u = __builtin_bit_cast(unsigned int, x);
    return (unsigned short)((u + 0x7fffu + ((u >> 16) & 1u)) >> 16);
}

static __device__ __forceinline__ unsigned cvt_pk_bf16(float lo, float hi) {
    unsigned r;
    asm("v_cvt_pk_bf16_f32 %0, %1, %2" : "=v"(r) : "v"(lo), "v"(hi));
    return r;
}

// ws layout (floats):
//   [0,1024)    wx_frag: [4 m][64 lane] x 8 bf16, rows prescaled; k=12 = fused bias
//   [1024,3072) wh_frag: [4 m][2 kt][64 lane] x 8 bf16, rows prescaled
//   [3072,3104) whead:   [2 hi][16 q] f32 permuted to C-layout rows
__global__ void prep_kernel(const float* __restrict__ Wih, const float* __restrict__ Whh,
                            const float* __restrict__ bih, const float* __restrict__ bhh,
                            const float* __restrict__ Whead, float* __restrict__ ws) {
    const int tid = threadIdx.x;  // 256
    unsigned short* wx = (unsigned short*)ws;
    unsigned short* wh = (unsigned short*)(ws + 1024);
    float* whd = ws + 3072;

    {   // wx: entry = m*64 + lane (== tid)
        int m = tid >> 6, lane = tid & 63;
        int g = 32 * m + (lane & 31);
        float scale = (m == 2) ? TWOLOG2E : -LOG2E;   // g-gate: +2log2e; i,f,o: -log2e
        int kbase = 8 * (lane >> 5);
        for (int j = 0; j < 8; ++j) {
            int k = kbase + j;
            float v = 0.0f;
            if (k < F_IN)       v = Wih[g * F_IN + k];
            else if (k == F_IN) v = bih[g] + bhh[g];
            wx[tid * 8 + j] = f2bf(scale * v);
        }
    }
    for (int e = tid; e < 4 * 2 * 64; e += 256) {
        int m = e >> 7, kt = (e >> 6) & 1, lane = e & 63;
        int g = 32 * m + (lane & 31);
        float scale = (m == 2) ? TWOLOG2E : -LOG2E;
        int kbase = 16 * kt + 8 * (lane >> 5);
        for (int j = 0; j < 8; ++j)
            wh[e * 8 + j] = f2bf(scale * Whh[g * HID + kbase + j]);
    }
    if (tid < 32) {
        int hi = tid >> 4, q = tid & 15;
        int j = (q & 3) + 8 * (q >> 2) + 4 * hi;
        whd[tid] = Whead[j];
    }
}

// r10 instruction stream, 1-WAVE workgroups: finest scheduler packing
// granularity. (64,3) caps unified regs at 170 >= ~140 used -> no spill
// (r3/r4's failure was cap 128 < need). No LDS, no barriers.
__global__ void __launch_bounds__(64, 3)
lstm_kernel(const float* __restrict__ x, const float* __restrict__ ws,
            const float* __restrict__ bheadp, float* __restrict__ out, int B) {
    const int lane = threadIdx.x;   // 0..63
    const int col  = lane & 31;
    const int hi   = lane >> 5;
    int b = blockIdx.x * 32 + col;
    const bool valid = (b < B);
    if (b >= B) b = B - 1;

    const bf16x8* wxp = (const bf16x8*)ws;
    const bf16x8* whp = (const bf16x8*)(ws + 1024);
    bf16x8 wxf[4], whf[4][2];
#pragma unroll
    for (int m = 0; m < 4; ++m) wxf[m] = wxp[m * 64 + lane];
#pragma unroll
    for (int m = 0; m < 4; ++m)
#pragma unroll
        for (int kt = 0; kt < 2; ++kt) whf[m][kt] = whp[(m * 2 + kt) * 64 + lane];

    // lo lanes read x[0..3],x[4..7]; hi lanes read x[8..11] (2nd load unused there)
    const float* xb1 = x + (size_t)b * (T_STEPS * F_IN) + (hi ? 8 : 0);
    const float* xb2 = x + (size_t)b * (T_STEPS * F_IN) + (hi ? 8 : 4);

    f32x2 c2[8], hv2[8];
#pragma unroll
    for (int p = 0; p < 8; ++p) { c2[p] = (f32x2){0.f, 0.f}; hv2[p] = (f32x2){0.f, 0.f}; }
    bf16x8 hf0, hf1;
#pragma unroll
    for (int j = 0; j < 8; ++j) { hf0[j] = 0; hf1[j] = 0; }

    for (int t = 0; t < T_STEPS; ++t) {
        float4 va = *(const float4*)(xb1 + t * F_IN);
        float4 vb = *(const float4*)(xb2 + t * F_IN);

        FragU xf;
        xf.u[0] = cvt_pk_bf16(va.x, va.y);
        xf.u[1] = cvt_pk_bf16(va.z, va.w);
        unsigned w2 = cvt_pk_bf16(vb.x, vb.y);
        unsigned w3 = cvt_pk_bf16(vb.z, vb.w);
        xf.u[2] = hi ? 0x00003f80u : w2;   // k=12 -> 1.0 (fused bias feature)
        xf.u[3] = hi ? 0u : w3;

        f32x16 a0, a1, a2, a3;
#pragma unroll
        for (int q = 0; q < 16; ++q) { a0[q] = 0.f; a1[q] = 0.f; a2[q] = 0.f; a3[q] = 0.f; }

        a0 = __builtin_amdgcn_mfma_f32_32x32x16_bf16(wxf[0], xf.v, a0, 0, 0, 0);
        a1 = __builtin_amdgcn_mfma_f32_32x32x16_bf16(wxf[1], xf.v, a1, 0, 0, 0);
        a2 = __builtin_amdgcn_mfma_f32_32x32x16_bf16(wxf[2], xf.v, a2, 0, 0, 0);
        a3 = __builtin_amdgcn_mfma_f32_32x32x16_bf16(wxf[3], xf.v, a3, 0, 0, 0);
        a0 = __builtin_amdgcn_mfma_f32_32x32x16_bf16(whf[0][0], hf0, a0, 0, 0, 0);
        a1 = __builtin_amdgcn_mfma_f32_32x32x16_bf16(whf[1][0], hf0, a1, 0, 0, 0);
        a2 = __builtin_amdgcn_mfma_f32_32x32x16_bf16(whf[2][0], hf0, a2, 0, 0, 0);
        a3 = __builtin_amdgcn_mfma_f32_32x32x16_bf16(whf[3][0], hf0, a3, 0, 0, 0);
        a0 = __builtin_amdgcn_mfma_f32_32x32x16_bf16(whf[0][1], hf1, a0, 0, 0, 0);
        a1 = __builtin_amdgcn_mfma_f32_32x32x16_bf16(whf[1][1], hf1, a1, 0, 0, 0);
        a2 = __builtin_amdgcn_mfma_f32_32x32x16_bf16(whf[2][1], hf1, a2, 0, 0, 0);
        a3 = __builtin_amdgcn_mfma_f32_32x32x16_bf16(whf[3][1], hf1, a3, 0, 0, 0);

        // Fused-rcp cell, f32x2-packed full-rate math, scalar trans (7/unit).
        const f32x2 one2 = {1.0f, 1.0f};
#pragma unroll
        for (int p = 0; p < 8; ++p) {
            const int q0 = 2 * p, q1 = 2 * p + 1;
            f32x2 ei = {__builtin_amdgcn_exp2f(a0[q0]), __builtin_amdgcn_exp2f(a0[q1])};
            f32x2 ef = {__builtin_amdgcn_exp2f(a1[q0]), __builtin_amdgcn_exp2f(a1[q1])};
            f32x2 eg = {__builtin_amdgcn_exp2f(a2[q0]), __builtin_amdgcn_exp2f(a2[q1])};
            f32x2 eo = {__builtin_amdgcn_exp2f(a3[q0]), __builtin_amdgcn_exp2f(a3[q1])};
            f32x2 A  = (one2 + ei) * (one2 + eg);
            f32x2 F  = one2 + ef;
            f32x2 FA = F * A;
            f32x2 r1 = {__builtin_amdgcn_rcpf(FA.x), __builtin_amdgcn_rcpf(FA.y)};
            f32x2 t2 = eg * (f32x2){TWOLOG2E, TWOLOG2E} - (f32x2){TWOLOG2E, TWOLOG2E};
            f32x2 num = t2 * F + c2[p] * A;
            c2[p] = num * r1;
            f32x2 ec = {__builtin_amdgcn_exp2f(c2[p].x), __builtin_amdgcn_exp2f(c2[p].y)};
            f32x2 r2in = (one2 + eo) * (one2 + ec);
            f32x2 r2 = {__builtin_amdgcn_rcpf(r2in.x), __builtin_amdgcn_rcpf(r2in.y)};
            hv2[p] = (ec - one2) * r2;
        }

        // repack h (C-layout) -> next B-fragments
        unsigned P0 = cvt_pk_bf16(hv2[0].x, hv2[0].y);
        unsigned P1 = cvt_pk_bf16(hv2[1].x, hv2[1].y);
        unsigned P2 = cvt_pk_bf16(hv2[2].x, hv2[2].y);
        unsigned P3 = cvt_pk_bf16(hv2[3].x, hv2[3].y);
        unsigned P4 = cvt_pk_bf16(hv2[4].x, hv2[4].y);
        unsigned P5 = cvt_pk_bf16(hv2[5].x, hv2[5].y);
        unsigned P6 = cvt_pk_bf16(hv2[6].x, hv2[6].y);
        unsigned P7 = cvt_pk_bf16(hv2[7].x, hv2[7].y);
        asm("v_permlane32_swap_b32 %0, %1" : "+v"(P0), "+v"(P2));
        asm("v_permlane32_swap_b32 %0, %1" : "+v"(P1), "+v"(P3));
        asm("v_permlane32_swap_b32 %0, %1" : "+v"(P4), "+v"(P6));
        asm("v_permlane32_swap_b32 %0, %1" : "+v"(P5), "+v"(P7));
        FragU h0; h0.u[0] = P0; h0.u[1] = P1; h0.u[2] = P2; h0.u[3] = P3;
        FragU h1; h1.u[0] = P4; h1.u[1] = P5; h1.u[2] = P6; h1.u[3] = P7;
        hf0 = h0.v;
        hf1 = h1.v;
    }

    // head: y = h . Whead + bhead ; softplus
    const float* whd = ws + 3072 + hi * 16;
    float y = 0.0f;
#pragma unroll
    for (int p = 0; p < 8; ++p) {
        y = fmaf(hv2[p].x, whd[2 * p],     y);
        y = fmaf(hv2[p].y, whd[2 * p + 1], y);
    }
    y += __shfl_xor(y, 32, 64);
    y += bheadp[0];
    float sp = fmaxf(y, 0.0f) + log1pf(expf(-fabsf(y)));
    if (valid && hi == 0) out[b] = sp;
}

extern "C" void kernel_launch(void* const* d_in, const int* in_sizes, int n_in,
                              void* d_out, int out_size, void* d_ws, size_t ws_size,
                              hipStream_t stream) {
    const float* x     = (const float*)d_in[0];
    const float* Wih   = (const float*)d_in[1];
    const float* Whh   = (const float*)d_in[2];
    const float* bih   = (const float*)d_in[3];
    const float* bhh   = (const float*)d_in[4];
    const float* Whead = (const float*)d_in[5];
    const float* bhead = (const float*)d_in[6];
    float* out = (float*)d_out;
    float* ws  = (float*)d_ws;

    const int B = in_sizes[0] / (T_STEPS * F_IN);
    const int blocks = (B + 31) / 32;

    hipLaunchKernelGGL(prep_kernel, dim3(1), dim3(256), 0, stream,
                       Wih, Whh, bih, bhh, Whead, ws);
    hipLaunchKernelGGL(lstm_kernel, dim3(blocks), dim3(64), 0, stream,
                       x, ws, bhead, out, B);
}